// Round 5
// baseline (306.879 us; speedup 1.0000x reference)
//
#include <hip/hip_runtime.h>

#define BB 64
#define NN 1024
#define TI 4          // i-rows per block in kC

typedef float vf4 __attribute__((ext_vector_type(4)));

// out layout (floats):
//   [0] done | [1..1+B*N) new_mask | [1+B*N..) adj | fa[B], ptn[B], step[B]
#define OFF_NM   1L
#define OFF_ADJ  (1L + (long)BB * NN)
#define OFF_FA   (OFF_ADJ + (long)BB * NN * NN)

// ws layout (floats, SoA planes):
//   cl[B*N] @0, du[B*N] @65536, nm[B*N] @131072, dl[N] @196608,
//   rowsc float2[B*N] @197632
#define WS_DU   (BB * NN)
#define WS_NM   (2 * BB * NN)
#define WS_DL   (3 * BB * NN)
#define WS_RS   (3 * BB * NN + NN)

__global__ __launch_bounds__(256) void kA(const float* __restrict__ inputs,
                                          const float* __restrict__ dist,
                                          const float* __restrict__ mask,
                                          const float* __restrict__ pt,
                                          const int*   __restrict__ pa,
                                          const int*   __restrict__ fa,
                                          float* __restrict__ out,
                                          float* __restrict__ ws) {
    int gid = blockIdx.x * 256 + threadIdx.x;   // b*N + j
    int b = gid >> 10;
    int j = gid & (NN - 1);
    int p = pa[b];
    float ptb = pt[b];
    const float* row = inputs + (size_t)gid * 4;
    float op = row[0], cl = row[1], du = row[2];
    float tt = inputs[3];                        // inputs[0,0,ARR]
    float dl = dist[(size_t)j * NN + (NN - 1)];  // dlast[j]
    float arr = dist[(size_t)p * NN + j] + ptb;  // arrive == farrive
    float w = fmaxf(0.0f, op - arr);
    float t = arr + w;
    bool c1 = (t <= cl);
    bool c2 = (((t + du) + dl) <= tt);
    float m = (j == p) ? 0.0f : mask[gid];
    float nm = (c1 && c2) ? m : 0.0f;
    float fp = t + du;                           // (farrive + fwait) + durat
    out[OFF_NM + gid] = nm;
    ws[gid]          = cl;
    ws[WS_DU + gid]  = du;
    ws[WS_NM + gid]  = nm;
    if (b == 0) ws[WS_DL + j] = dl;
    ((float2*)(ws + WS_RS))[gid] = make_float2(fp, op);

    // ---- folded kB: block 0, wave 0 (lanes 0..63 == b index) ----
    if (blockIdx.x == 0 && threadIdx.x < 64) {
        int bb = threadIdx.x;
        int pp = pa[bb];
        float ptbb = pt[bb];
        const float* rw = inputs + (size_t)(bb * NN + (NN - 1)) * 4;
        float op2 = rw[0], cl2 = rw[1], du2 = rw[2];
        float dl2 = dist[(size_t)(NN - 1) * NN + (NN - 1)];
        float ar2 = dist[(size_t)pp * NN + (NN - 1)] + ptbb;
        float w2 = fmaxf(0.0f, op2 - ar2);
        float t2 = ar2 + w2;
        bool alive = (t2 <= cl2) && (((t2 + du2) + dl2) <= inputs[3]);
        float mm = ((NN - 1) == pp) ? 0.0f : mask[bb * NN + (NN - 1)];
        float nm2 = alive ? mm : 0.0f;
        unsigned long long ball = __ballot(nm2 > 0.0f);
        if (bb == 0) out[0] = (ball == 0ULL) ? 1.0f : 0.0f;

        int f = fa[bb];
        float arrj = dist[(size_t)pp * NN + f] + ptbb;
        const float* frow = inputs + (size_t)(bb * NN + f) * 4;
        float wj = fmaxf(0.0f, frow[0] - arrj);
        float ptn = (arrj + wj) + frow[2];
        out[OFF_FA + bb]          = (float)f;
        out[OFF_FA + BB + bb]     = ptn;
        out[OFF_FA + 2 * BB + bb] = 1.0f;
    }
}

__global__ __launch_bounds__(256) void kC(const float* __restrict__ ws,
                                          const float* __restrict__ inputs,
                                          const float* __restrict__ dist,
                                          float* __restrict__ out) {
    __shared__ float lv[TI][NN];
    // i-major swizzle: blocks sharing the same dist rows are dispatch-adjacent
    int b  = blockIdx.x & (BB - 1);
    int i0 = (blockIdx.x >> 6) * TI;
    int t = threadIdx.x;
    int j0 = t * 4;

    // per-(b,j) column params, reused for all TI rows
    float4 cl4 = *(const float4*)(ws + (size_t)b * NN + j0);
    float4 du4 = *(const float4*)(ws + WS_DU + (size_t)b * NN + j0);
    float4 nm4 = *(const float4*)(ws + WS_NM + (size_t)b * NN + j0);
    float4 dl4 = *(const float4*)(ws + WS_DL + j0);
    float clv[4] = {cl4.x, cl4.y, cl4.z, cl4.w};
    float duv[4] = {du4.x, du4.y, du4.z, du4.w};
    float nmv[4] = {nm4.x, nm4.y, nm4.z, nm4.w};
    float dlv[4] = {dl4.x, dl4.y, dl4.z, dl4.w};
    float tt_b = inputs[(size_t)b * NN * 4 + 3];
    const float2* rs = (const float2*)(ws + WS_RS) + (size_t)b * NN + i0;

#pragma unroll
    for (int g = 0; g < TI; ++g) {
        int i = i0 + g;
        float2 r = rs[g];                          // wave-uniform
        float fp = r.x, op_i = r.y;
        float4 d4 = *(const float4*)(dist + (size_t)i * NN + j0);
        float dv[4] = {d4.x, d4.y, d4.z, d4.w};
        float v[4];
#pragma unroll
        for (int u = 0; u < 4; ++u) {
            float arr2 = dv[u] + fp;
            float w2 = fmaxf(0.0f, op_i - arr2);
            float s = arr2 + w2;
            bool a1 = (s <= clv[u]);
            bool a2 = (((s + duv[u]) + dlv[u]) <= tt_b);
            v[u] = (a1 && a2) ? nmv[u] : 0.0f;
            if (j0 + u == i) v[u] = 1.0f;
        }
        *(vf4*)(&lv[g][j0]) = (vf4){v[0], v[1], v[2], v[3]};
    }
    __syncthreads();

    // aligned 16B NT stores; row base ≡ 1 (mod 4) so quads start at j=3
#pragma unroll
    for (int g = 0; g < TI; ++g) {
        float* orow = out + OFF_ADJ + ((size_t)(b * NN + i0 + g)) * NN;
        if (t < 255) {
            int js = 3 + 4 * t;
            vf4 wv = {lv[g][js], lv[g][js + 1], lv[g][js + 2], lv[g][js + 3]};
            __builtin_nontemporal_store(wv, (vf4*)(orow + js));
        } else {
            __builtin_nontemporal_store(lv[g][0], orow + 0);
            __builtin_nontemporal_store(lv[g][1], orow + 1);
            __builtin_nontemporal_store(lv[g][2], orow + 2);
            __builtin_nontemporal_store(lv[g][NN - 1], orow + (NN - 1));
        }
    }
}

extern "C" void kernel_launch(void* const* d_in, const int* in_sizes, int n_in,
                              void* d_out, int out_size, void* d_ws, size_t ws_size,
                              hipStream_t stream) {
    const float* inputs = (const float*)d_in[0];   // (B,N,4)
    const float* dist   = (const float*)d_in[1];   // (N,N)
    const float* mask   = (const float*)d_in[2];   // (B,N)
    const float* pt     = (const float*)d_in[3];   // (B,1)
    const int*   pa     = (const int*)d_in[4];     // (B,)
    const int*   fa     = (const int*)d_in[5];     // (B,)
    float* out = (float*)d_out;
    float* ws  = (float*)d_ws;

    kA<<<(BB * NN) / 256, 256, 0, stream>>>(inputs, dist, mask, pt, pa, fa, out, ws);
    kC<<<BB * (NN / TI), 256, 0, stream>>>(ws, inputs, dist, out);
}

// Round 6
// 294.368 us; speedup vs baseline: 1.0425x; 1.0425x over previous
//
#include <hip/hip_runtime.h>

#define BB 64
#define NN 1024
#define TI 4          // i-rows per block in kC

typedef float vf4 __attribute__((ext_vector_type(4)));

// out layout (floats):
//   [0] done | [1..1+B*N) new_mask | [1+B*N..) adj | fa[B], ptn[B], step[B]
#define OFF_NM   1L
#define OFF_ADJ  (1L + (long)BB * NN)
#define OFF_FA   (OFF_ADJ + (long)BB * NN * NN)

// ws layout (floats, SoA planes):
//   cl[B*N] @0, du[B*N] @65536, nm[B*N] @131072, dl[N] @196608,
//   rowsc float2[B*N] @197632
#define WS_DU   (BB * NN)
#define WS_NM   (2 * BB * NN)
#define WS_DL   (3 * BB * NN)
#define WS_RS   (3 * BB * NN + NN)

__global__ __launch_bounds__(256) void kA(const float* __restrict__ inputs,
                                          const float* __restrict__ dist,
                                          const float* __restrict__ mask,
                                          const float* __restrict__ pt,
                                          const int*   __restrict__ pa,
                                          const int*   __restrict__ fa,
                                          float* __restrict__ out,
                                          float* __restrict__ ws) {
    int gid = blockIdx.x * 256 + threadIdx.x;   // b*N + j
    int b = gid >> 10;
    int j = gid & (NN - 1);
    int p = pa[b];
    float ptb = pt[b];
    const float* row = inputs + (size_t)gid * 4;
    float op = row[0], cl = row[1], du = row[2];
    float tt = inputs[3];                        // inputs[0,0,ARR]
    float dl = dist[(size_t)j * NN + (NN - 1)];  // dlast[j]
    float arr = dist[(size_t)p * NN + j] + ptb;  // arrive == farrive
    float w = fmaxf(0.0f, op - arr);
    float t = arr + w;
    bool c1 = (t <= cl);
    bool c2 = (((t + du) + dl) <= tt);
    float m = (j == p) ? 0.0f : mask[gid];
    float nm = (c1 && c2) ? m : 0.0f;
    float fp = t + du;                           // (farrive + fwait) + durat
    out[OFF_NM + gid] = nm;
    ws[gid]          = cl;
    ws[WS_DU + gid]  = du;
    ws[WS_NM + gid]  = nm;
    if (b == 0) ws[WS_DL + j] = dl;
    ((float2*)(ws + WS_RS))[gid] = make_float2(fp, op);

    // ---- folded kB: block 0, wave 0 (lanes 0..63 == b index) ----
    if (blockIdx.x == 0 && threadIdx.x < 64) {
        int bb = threadIdx.x;
        int pp = pa[bb];
        float ptbb = pt[bb];
        const float* rw = inputs + (size_t)(bb * NN + (NN - 1)) * 4;
        float op2 = rw[0], cl2 = rw[1], du2 = rw[2];
        float dl2 = dist[(size_t)(NN - 1) * NN + (NN - 1)];
        float ar2 = dist[(size_t)pp * NN + (NN - 1)] + ptbb;
        float w2 = fmaxf(0.0f, op2 - ar2);
        float t2 = ar2 + w2;
        bool alive = (t2 <= cl2) && (((t2 + du2) + dl2) <= inputs[3]);
        float mm = ((NN - 1) == pp) ? 0.0f : mask[bb * NN + (NN - 1)];
        float nm2 = alive ? mm : 0.0f;
        unsigned long long ball = __ballot(nm2 > 0.0f);
        if (bb == 0) out[0] = (ball == 0ULL) ? 1.0f : 0.0f;

        int f = fa[bb];
        float arrj = dist[(size_t)pp * NN + f] + ptbb;
        const float* frow = inputs + (size_t)(bb * NN + f) * 4;
        float wj = fmaxf(0.0f, frow[0] - arrj);
        float ptn = (arrj + wj) + frow[2];
        out[OFF_FA + bb]          = (float)f;
        out[OFF_FA + BB + bb]     = ptn;
        out[OFF_FA + 2 * BB + bb] = 1.0f;
    }
}

__global__ __launch_bounds__(256) void kC(const float* __restrict__ ws,
                                          const float* __restrict__ inputs,
                                          const float* __restrict__ dist,
                                          float* __restrict__ out) {
    __shared__ float lv[TI][NN];
    // b-major: consecutive blocks share b and write adjacent 16KB ranges
    int b  = blockIdx.x >> 8;               // NN/TI = 256 tiles per b
    int i0 = (blockIdx.x & 255) * TI;
    int t = threadIdx.x;
    int j0 = t * 4;

    // per-(b,j) column params, held in registers for all TI rows
    float4 cl4 = *(const float4*)(ws + (size_t)b * NN + j0);
    float4 du4 = *(const float4*)(ws + WS_DU + (size_t)b * NN + j0);
    float4 nm4 = *(const float4*)(ws + WS_NM + (size_t)b * NN + j0);
    float4 dl4 = *(const float4*)(ws + WS_DL + j0);
    float clv[4] = {cl4.x, cl4.y, cl4.z, cl4.w};
    float duv[4] = {du4.x, du4.y, du4.z, du4.w};
    float nmv[4] = {nm4.x, nm4.y, nm4.z, nm4.w};
    float dlv[4] = {dl4.x, dl4.y, dl4.z, dl4.w};
    float tt_b = inputs[(size_t)b * NN * 4 + 3];
    const float2* rs = (const float2*)(ws + WS_RS) + (size_t)b * NN + i0;

#pragma unroll
    for (int g = 0; g < TI; ++g) {
        int i = i0 + g;
        float2 r = rs[g];                          // wave-uniform
        float fp = r.x, op_i = r.y;
        float4 d4 = *(const float4*)(dist + (size_t)i * NN + j0);
        float dv[4] = {d4.x, d4.y, d4.z, d4.w};
        float v[4];
#pragma unroll
        for (int u = 0; u < 4; ++u) {
            float arr2 = dv[u] + fp;
            float w2 = fmaxf(0.0f, op_i - arr2);
            float s = arr2 + w2;
            bool a1 = (s <= clv[u]);
            bool a2 = (((s + duv[u]) + dlv[u]) <= tt_b);
            v[u] = (a1 && a2) ? nmv[u] : 0.0f;
            if (j0 + u == i) v[u] = 1.0f;
        }
        *(vf4*)(&lv[g][j0]) = (vf4){v[0], v[1], v[2], v[3]};
    }
    __syncthreads();

    // aligned 16B NT stores; row base ≡ 1 (mod 4) so quads start at j=3
#pragma unroll
    for (int g = 0; g < TI; ++g) {
        float* orow = out + OFF_ADJ + ((size_t)(b * NN + i0 + g)) * NN;
        if (t < 255) {
            int js = 3 + 4 * t;
            vf4 wv = {lv[g][js], lv[g][js + 1], lv[g][js + 2], lv[g][js + 3]};
            __builtin_nontemporal_store(wv, (vf4*)(orow + js));
        } else {
            __builtin_nontemporal_store(lv[g][0], orow + 0);
            __builtin_nontemporal_store(lv[g][1], orow + 1);
            __builtin_nontemporal_store(lv[g][2], orow + 2);
            __builtin_nontemporal_store(lv[g][NN - 1], orow + (NN - 1));
        }
    }
}

extern "C" void kernel_launch(void* const* d_in, const int* in_sizes, int n_in,
                              void* d_out, int out_size, void* d_ws, size_t ws_size,
                              hipStream_t stream) {
    const float* inputs = (const float*)d_in[0];   // (B,N,4)
    const float* dist   = (const float*)d_in[1];   // (N,N)
    const float* mask   = (const float*)d_in[2];   // (B,N)
    const float* pt     = (const float*)d_in[3];   // (B,1)
    const int*   pa     = (const int*)d_in[4];     // (B,)
    const int*   fa     = (const int*)d_in[5];     // (B,)
    float* out = (float*)d_out;
    float* ws  = (float*)d_ws;

    kA<<<(BB * NN) / 256, 256, 0, stream>>>(inputs, dist, mask, pt, pa, fa, out, ws);
    kC<<<BB * (NN / TI), 256, 0, stream>>>(ws, inputs, dist, out);
}

// Round 7
// 284.266 us; speedup vs baseline: 1.0795x; 1.0355x over previous
//
#include <hip/hip_runtime.h>

#define BB 64
#define NN 1024

typedef float vf4 __attribute__((ext_vector_type(4)));

// out layout (floats):
//   [0] done | [1..1+B*N) new_mask | [1+B*N..) adj | fa[B], ptn[B], step[B]
#define OFF_NM   1L
#define OFF_ADJ  (1L + (long)BB * NN)
#define OFF_FA   (OFF_ADJ + (long)BB * NN * NN)

// ws layout (floats):
//   sstar[B*N] @0 ; rowsc float2[B*N] @ BB*NN
#define WS_RS   (BB * NN)

__global__ __launch_bounds__(256) void kA(const float* __restrict__ inputs,
                                          const float* __restrict__ dist,
                                          const float* __restrict__ mask,
                                          const float* __restrict__ pt,
                                          const int*   __restrict__ pa,
                                          const int*   __restrict__ fa,
                                          float* __restrict__ out,
                                          float* __restrict__ ws) {
    int gid = blockIdx.x * 256 + threadIdx.x;   // b*N + j
    int b = gid >> 10;
    int j = gid & (NN - 1);
    int p = pa[b];
    float ptb = pt[b];
    const float* row = inputs + (size_t)gid * 4;
    float op = row[0], cl = row[1], du = row[2];
    float tt = inputs[3];                        // inputs[0,0,ARR]
    float dl = dist[(size_t)j * NN + (NN - 1)];  // dlast[j]
    float arr = dist[(size_t)p * NN + j] + ptb;  // arrive == farrive
    float w = fmaxf(0.0f, op - arr);
    float t = arr + w;
    bool c1 = (t <= cl);
    bool c2 = (((t + du) + dl) <= tt);
    float m = (j == p) ? 0.0f : mask[gid];
    float nm = (c1 && c2) ? m : 0.0f;
    float fp = t + du;                           // (farrive + fwait) + durat
    out[OFF_NM + gid] = nm;

    // S* = min(cl, Smax) where Smax = largest float s>=0 with
    // fl(fl(s+du)+dl) <= tt  (h is weakly monotone in s under RN rounding).
    // nm==0 folds to S*=-1 (s>=0 always, so compare is false).
    float sstar = -1.0f;
    if (nm > 0.0f) {
        unsigned u = 0u;
        #pragma unroll
        for (int k = 30; k >= 0; --k) {
            unsigned cand = u | (1u << k);
            float s = __uint_as_float(cand);   // NaN cands auto-rejected
            if (((s + du) + dl) <= tt) u = cand;
        }
        float su = __uint_as_float(u);
        if (((su + du) + dl) <= tt) sstar = fminf(cl, su);
        // else: even s=0 fails -> keep -1
    }
    ws[gid] = sstar;
    ((float2*)(ws + WS_RS))[gid] = make_float2(fp, op);

    // ---- folded kB: block 0, wave 0 (lanes 0..63 == b index) ----
    if (blockIdx.x == 0 && threadIdx.x < 64) {
        int bb = threadIdx.x;
        int pp = pa[bb];
        float ptbb = pt[bb];
        const float* rw = inputs + (size_t)(bb * NN + (NN - 1)) * 4;
        float op2 = rw[0], cl2 = rw[1], du2 = rw[2];
        float dl2 = dist[(size_t)(NN - 1) * NN + (NN - 1)];
        float ar2 = dist[(size_t)pp * NN + (NN - 1)] + ptbb;
        float w2 = fmaxf(0.0f, op2 - ar2);
        float t2 = ar2 + w2;
        bool alive = (t2 <= cl2) && (((t2 + du2) + dl2) <= inputs[3]);
        float mm = ((NN - 1) == pp) ? 0.0f : mask[bb * NN + (NN - 1)];
        float nm2 = alive ? mm : 0.0f;
        unsigned long long ball = __ballot(nm2 > 0.0f);
        if (bb == 0) out[0] = (ball == 0ULL) ? 1.0f : 0.0f;

        int f = fa[bb];
        float arrj = dist[(size_t)pp * NN + f] + ptbb;
        const float* frow = inputs + (size_t)(bb * NN + f) * 4;
        float wj = fmaxf(0.0f, frow[0] - arrj);
        float ptn = (arrj + wj) + frow[2];
        out[OFF_FA + bb]          = (float)f;
        out[OFF_FA + BB + bb]     = ptn;
        out[OFF_FA + 2 * BB + bb] = 1.0f;
    }
}

__global__ __launch_bounds__(256) void kC(const float* __restrict__ ws,
                                          const float* __restrict__ dist,
                                          float* __restrict__ out) {
    __shared__ float lv[NN];
    int blk = blockIdx.x;          // b*N + i  (b-major, unblocked: R4 shape)
    int b = blk >> 10;
    int i = blk & (NN - 1);
    float2 r = ((const float2*)(ws + WS_RS))[blk];   // wave-uniform
    float fp = r.x, op_i = r.y;

    int t = threadIdx.x;
    int j0 = t * 4;
    float4 d4 = *(const float4*)(dist + (size_t)i * NN + j0);
    float4 s4 = *(const float4*)(ws + (size_t)b * NN + j0);
    float dv[4] = {d4.x, d4.y, d4.z, d4.w};
    float sv[4] = {s4.x, s4.y, s4.z, s4.w};
    float v[4];
#pragma unroll
    for (int u = 0; u < 4; ++u) {
        float arr2 = dv[u] + fp;
        float w2 = fmaxf(0.0f, op_i - arr2);
        float s = arr2 + w2;
        v[u] = (s <= sv[u]) ? 1.0f : 0.0f;
        if (j0 + u == i) v[u] = 1.0f;
    }
    *(vf4*)(lv + j0) = (vf4){v[0], v[1], v[2], v[3]};
    __syncthreads();

    // aligned 16B NT stores; row base ≡ 1 (mod 4) so quads start at j=3
    float* orow = out + OFF_ADJ + (size_t)blk * NN;
    if (t < 255) {
        int js = 3 + 4 * t;
        vf4 wv = {lv[js], lv[js + 1], lv[js + 2], lv[js + 3]};
        __builtin_nontemporal_store(wv, (vf4*)(orow + js));
    } else {
        __builtin_nontemporal_store(lv[0], orow + 0);
        __builtin_nontemporal_store(lv[1], orow + 1);
        __builtin_nontemporal_store(lv[2], orow + 2);
        __builtin_nontemporal_store(lv[NN - 1], orow + (NN - 1));
    }
}

extern "C" void kernel_launch(void* const* d_in, const int* in_sizes, int n_in,
                              void* d_out, int out_size, void* d_ws, size_t ws_size,
                              hipStream_t stream) {
    const float* inputs = (const float*)d_in[0];   // (B,N,4)
    const float* dist   = (const float*)d_in[1];   // (N,N)
    const float* mask   = (const float*)d_in[2];   // (B,N)
    const float* pt     = (const float*)d_in[3];   // (B,1)
    const int*   pa     = (const int*)d_in[4];     // (B,)
    const int*   fa     = (const int*)d_in[5];     // (B,)
    float* out = (float*)d_out;
    float* ws  = (float*)d_ws;

    kA<<<(BB * NN) / 256, 256, 0, stream>>>(inputs, dist, mask, pt, pa, fa, out, ws);
    kC<<<BB * NN, 256, 0, stream>>>(ws, dist, out);
}